// Round 7
// baseline (176.927 us; speedup 1.0000x reference)
//
#include <hip/hip_runtime.h>
#include <math.h>

// Native clang vector (HIP_vector_type rejected by nontemporal builtins / asm "v").
typedef float fvec4 __attribute__((ext_vector_type(4)));

// my_ceil(y) = sum_{k=1..150} sigmoid(100(y-k)) + sigmoid(100(y+k)) - 150
// Closed form (verified passing; absmax 0.25 is the harness's bf16-stored
// reference quantization at |y|~150, not our error):
//   r = rint(y), d = y - r, s = sigmoid(100 d)
//   r >=  1 : (r-1) + s ;  r <= -1 : r + s ;  r == 0 : 0 ; clamp [-150,150]
__device__ __forceinline__ float my_ceil1(float y) {
    float r = rintf(y);
    float d = y - r;
    float e = __expf(-100.0f * d);                 // v_mul + v_exp_f32
    float s = __builtin_amdgcn_rcpf(1.0f + e);     // 1-instr reciprocal (~1 ulp)
    float f = (r >= 1.0f) ? (r - 1.0f + s)
            : (r <= -1.0f) ? (r + s)
            : 0.0f;
    return fminf(fmaxf(f, -150.0f), 150.0f);
}

__device__ __forceinline__ fvec4 my_ceil4(fvec4 v, fvec4 kc) {
    fvec4 o;
    o.x = my_ceil1(v.x * kc.x);
    o.y = my_ceil1(v.y * kc.y);
    o.z = my_ceil1(v.z * kc.z);
    o.w = my_ceil1(v.w * kc.w);
    return o;
}

// R6 post-mortem: 16 waves/CU x 8-deep forced MLP -> only ~53us. Same
// outstanding-load budget, rebalanced toward TLP: 4 streams/thread
// (forced co-live, ~40 VGPR) x 8 waves/SIMD (32 waves/CU, 2x R6).
// Cached loads (recover the ~50MB of L3 hits R1's counters showed);
// nontemporal stores (output never re-read; don't evict input from L3).
__global__ __launch_bounds__(256, 8) void quan_ceil_kernel(
        const fvec4* __restrict__ x4,
        const float* __restrict__ kern,   // 12 floats (C=12), broadcast
        fvec4* __restrict__ o4,
        int q) {                           // n4/4, divisible by 3
    int j = blockIdx.x * blockDim.x + threadIdx.x;
    if (j >= q) return;

    const fvec4* k4 = reinterpret_cast<const fvec4*>(kern);
    int g = j % 3;
    // ternary select, NOT a runtime-indexed array (avoids scratch, rule #20)
    fvec4 kc = (g == 0) ? k4[0] : (g == 1) ? k4[1] : k4[2];

    // q is uniform -> compiler keeps the 3 stream offsets in SGPR bases;
    // VGPR cost is just the data. Cached loads: input half-resident in L3.
    fvec4 a0 = x4[j];
    fvec4 a1 = x4[j + q];
    fvec4 a2 = x4[j + 2 * q];
    fvec4 a3 = x4[j + 3 * q];
    // Liveness barrier: all 4 vectors materialized here -> 4 back-to-back
    // global_load_dwordx4 issued before any compute (R5 showed the compiler
    // otherwise serializes to 1 outstanding load, VGPR_Count=16).
    asm volatile("" : "+v"(a0), "+v"(a1), "+v"(a2), "+v"(a3));

    __builtin_nontemporal_store(my_ceil4(a0, kc), &o4[j]);
    __builtin_nontemporal_store(my_ceil4(a1, kc), &o4[j + q]);
    __builtin_nontemporal_store(my_ceil4(a2, kc), &o4[j + 2 * q]);
    __builtin_nontemporal_store(my_ceil4(a3, kc), &o4[j + 3 * q]);
}

extern "C" void kernel_launch(void* const* d_in, const int* in_sizes, int n_in,
                              void* d_out, int out_size, void* d_ws, size_t ws_size,
                              hipStream_t stream) {
    const float* x = (const float*)d_in[0];
    const float* kern = (const float*)d_in[1];
    float* out = (float*)d_out;

    int n = in_sizes[0];   // 128*128*128*12 = 25,165,824
    int n4 = n / 4;        // 6,291,456 float4s
    int q = n4 / 4;        // 1,572,864 (divisible by 3 AND by 256)

    const int block = 256;
    int grid = (q + block - 1) / block;   // 6144 blocks, exact coverage

    quan_ceil_kernel<<<grid, block, 0, stream>>>(
        reinterpret_cast<const fvec4*>(x), kern,
        reinterpret_cast<fvec4*>(out), q);
}